// Round 8
// baseline (346.292 us; speedup 1.0000x reference)
//
#include <hip/hip_runtime.h>
#include <stdint.h>

// Problem constants (B=1)
#define SEQ   2048
#define EDIM  2048
#define NHQ   32
#define NHKV  8
#define HDIM  64
#define NQKV  3072   // 2048 (Q) + 512 (K) + 512 (V)

#define LOG2E 1.4426950408889634f

typedef __bf16 bf16x8 __attribute__((ext_vector_type(8)));
typedef float  f32x4  __attribute__((ext_vector_type(4)));

typedef __attribute__((address_space(1))) void gvoid;
typedef __attribute__((address_space(3))) void lvoid;

// fp32 -> bf16 bits, round-to-nearest-even
__device__ __forceinline__ unsigned short f2bf(float f) {
  unsigned int u = __builtin_bit_cast(unsigned int, f);
  u += 0x7FFFu + ((u >> 16) & 1u);
  return (unsigned short)(u >> 16);
}

// pack two fp32 -> one u32 of 2x bf16 (lo, hi)
__device__ __forceinline__ unsigned int pk2bf(float lo, float hi) {
  return (unsigned)f2bf(lo) | ((unsigned)f2bf(hi) << 16);
}

__device__ __forceinline__ float fexp2(float x) {
#if __has_builtin(__builtin_amdgcn_exp2f)
  return __builtin_amdgcn_exp2f(x);
#else
  return exp2f(x);
#endif
}

__device__ __forceinline__ bf16x8 ld_g16(const unsigned short* p) {
  uint4 u = *reinterpret_cast<const uint4*>(p);
  return __builtin_bit_cast(bf16x8, u);
}

// async global->LDS, 16B per lane. LDS dest is wave-uniform base + lane*16.
__device__ __forceinline__ void stage16(const void* g, void* l) {
  __builtin_amdgcn_global_load_lds((gvoid*)g, (lvoid*)l, 16, 0, 0);
}

// ---------------------------------------------------------------- conv x
__global__ __launch_bounds__(256) void conv_x_kernel(
    const float* __restrict__ x, unsigned short* __restrict__ xb) {
  int i = (blockIdx.x * 256 + threadIdx.x) * 8;
  float4 a = *reinterpret_cast<const float4*>(x + i);
  float4 b = *reinterpret_cast<const float4*>(x + i + 4);
  uint4 o;
  o.x = pk2bf(a.x, a.y);
  o.y = pk2bf(a.z, a.w);
  o.z = pk2bf(b.x, b.y);
  o.w = pk2bf(b.z, b.w);
  *reinterpret_cast<uint4*>(xb + i) = o;
}

// ------------------------------------------------- transpose W -> B^T bf16
// Builds WqkvT[n][k] (3072 x 2048) from Wq|Wk|Wv (k-major fp32).
__global__ __launch_bounds__(256) void tr_qkv_kernel(
    const float* __restrict__ Wq, const float* __restrict__ Wk,
    const float* __restrict__ Wv, unsigned short* __restrict__ Bt) {
  __shared__ float tile[32][33];
  const int tx = threadIdx.x, ty = threadIdx.y;
  const int kb = blockIdx.x * 32, nb = blockIdx.y * 32;
#pragma unroll
  for (int i = 0; i < 4; ++i) {
    int k = kb + ty + i * 8;
    int n = nb + tx;
    float v;
    if (n < 2048)      v = Wq[k * 2048 + n];
    else if (n < 2560) v = Wk[k * 512 + (n - 2048)];
    else               v = Wv[k * 512 + (n - 2560)];
    tile[ty + i * 8][tx] = v;
  }
  __syncthreads();
#pragma unroll
  for (int i = 0; i < 4; ++i) {
    int n = nb + ty + i * 8;
    int k = kb + tx;
    Bt[n * 2048 + k] = f2bf(tile[tx][ty + i * 8]);
  }
}

__global__ __launch_bounds__(256) void tr_wo_kernel(
    const float* __restrict__ Wo, unsigned short* __restrict__ Bt) {
  __shared__ float tile[32][33];
  const int tx = threadIdx.x, ty = threadIdx.y;
  const int kb = blockIdx.x * 32, nb = blockIdx.y * 32;
#pragma unroll
  for (int i = 0; i < 4; ++i)
    tile[ty + i * 8][tx] = Wo[(kb + ty + i * 8) * 2048 + nb + tx];
  __syncthreads();
#pragma unroll
  for (int i = 0; i < 4; ++i)
    Bt[(nb + ty + i * 8) * 2048 + kb + tx] = f2bf(tile[tx][ty + i * 8]);
}

// ---------------------------------------------------------------- GEMM
// C(M x N) = A(M x K, bf16 row-major) * Bt(N x K, bf16 row-major)^T
// BM=128, BN=64, BK=64. 4 waves (2x2); each wave owns 64x32 = 4x2 16x16
// frags. Grid is 1-D with bijective XCD swizzle (nwg%8==0).
// LDS: double-buffered As[128][64] + Bs[64][64] (48 KB) via global_load_lds
// with BOTH-SIDES XOR swizzle -> conflict-free ds_read_b128.
// MODE 0: epilogue = RoPE + split-store to Q[h][s][d], K[h][s][d], VT[h][d][s]
// MODE 1: plain fp32 store to Cout (N_=2048)
template <int MODE>
__global__ __launch_bounds__(256) void gemm_kernel(
    const unsigned short* __restrict__ A, const unsigned short* __restrict__ Bt,
    const float* __restrict__ freqs, unsigned short* __restrict__ Qb,
    unsigned short* __restrict__ Kb, unsigned short* __restrict__ VT,
    float* __restrict__ Cout, int N_, int K, int nwg) {
  __shared__ alignas(16) unsigned short As[2][128 * 64];
  __shared__ alignas(16) unsigned short Bs[2][64 * 64];
  const int t = threadIdx.x;
  const int w = t >> 6, l = t & 63;
  const int q = l >> 4, r16 = l & 15;
  const int wr = w >> 1, wc = w & 1;
  // bijective XCD swizzle (nwg % 8 == 0)
  const int cpx = nwg >> 3;
  const int id = (blockIdx.x & 7) * cpx + (blockIdx.x >> 3);
  const int brow = (id & 15) * 128;        // M=2048 -> 16 m-tiles
  const int bcol = (id >> 4) * 64;
  const unsigned short* Arow = A + (size_t)brow * K;
  const unsigned short* Brow = Bt + (size_t)bcol * K;
  f32x4 acc[4][2] = {};

#define STAGE_TILE(buf, ktb)                                                  \
  {                                                                           \
    _Pragma("unroll") for (int it = 0; it < 4; ++it) {                        \
      int sg = it * 256 + t;                                                  \
      int row = sg >> 3, ks = sg & 7;                                         \
      stage16(Arow + (size_t)row * K + (ktb) + ((ks ^ (row & 7)) << 3),       \
              (char*)As[buf] + sg * 16);                                      \
    }                                                                         \
    _Pragma("unroll") for (int it = 0; it < 2; ++it) {                        \
      int sg = it * 256 + t;                                                  \
      int row = sg >> 3, ks = sg & 7;                                         \
      stage16(Brow + (size_t)row * K + (ktb) + ((ks ^ (row & 7)) << 3),       \
              (char*)Bs[buf] + sg * 16);                                      \
    }                                                                         \
  }

  STAGE_TILE(0, 0)
  __syncthreads();

  for (int kt = 0; kt < K; kt += 64) {
    const int cur = (kt >> 6) & 1;
    if (kt + 64 < K) STAGE_TILE(cur ^ 1, kt + 64)
#pragma unroll
    for (int kk = 0; kk < 2; ++kk) {
      bf16x8 af[4], bfr[2];
#pragma unroll
      for (int mf = 0; mf < 4; ++mf) {
        int arow = wr * 64 + mf * 16 + r16;
        int slot = ((kk << 2) + q) ^ (arow & 7);
        af[mf] = *(const bf16x8*)(As[cur] + arow * 64 + slot * 8);
      }
#pragma unroll
      for (int nf = 0; nf < 2; ++nf) {
        int brw = wc * 32 + nf * 16 + r16;
        int slot = ((kk << 2) + q) ^ (brw & 7);
        bfr[nf] = *(const bf16x8*)(Bs[cur] + brw * 64 + slot * 8);
      }
#pragma unroll
      for (int mf = 0; mf < 4; ++mf)
#pragma unroll
        for (int nf = 0; nf < 2; ++nf)
          acc[mf][nf] = __builtin_amdgcn_mfma_f32_16x16x32_bf16(
              af[mf], bfr[nf], acc[mf][nf], 0, 0, 0);
    }
    __syncthreads();
  }

  // Epilogue. C-frag layout: col = lane&15, row = (lane>>4)*4 + reg.
#pragma unroll
  for (int mf = 0; mf < 4; ++mf) {
#pragma unroll
    for (int nf = 0; nf < 2; ++nf) {
      int j = bcol + wc * 32 + nf * 16 + r16;
#pragma unroll
      for (int reg = 0; reg < 4; ++reg) {
        float v = acc[mf][nf][reg];
        int srow = brow + wr * 64 + mf * 16 + q * 4 + reg;
        if (MODE == 1) {
          Cout[(size_t)srow * N_ + j] = v;
        } else {
          // column pairs (2i,2i+1) sit on adjacent lanes -> shfl_xor(1)
          float pv = __shfl_xor(v, 1);
          int d = j & 63;
          if (j < 2048) {  // Q, RoPE + (log2e)/sqrt(D) pre-scale
            float2 f = *reinterpret_cast<const float2*>(
                freqs + ((size_t)srow * 32 + (d >> 1)) * 2);
            float ov = (d & 1) ? (pv * f.y + v * f.x) : (v * f.x - pv * f.y);
            Qb[(size_t)(j >> 6) * (SEQ * HDIM) + srow * HDIM + d] =
                f2bf(ov * (0.125f * LOG2E));
          } else if (j < 2560) {  // K, RoPE
            float2 f = *reinterpret_cast<const float2*>(
                freqs + ((size_t)srow * 32 + (d >> 1)) * 2);
            float ov = (d & 1) ? (pv * f.y + v * f.x) : (v * f.x - pv * f.y);
            Kb[(size_t)((j - 2048) >> 6) * (SEQ * HDIM) + srow * HDIM + d] =
                f2bf(ov);
          } else {  // V, stored transposed [h][d][s]
            VT[(size_t)((j - 2560) >> 6) * (HDIM * SEQ) + d * SEQ + srow] =
                f2bf(v);
          }
        }
      }
    }
  }
#undef STAGE_TILE
}

// ------------------------------------------------------------ flash attn
// 32 q-rows/wave, KVBLK=128; 1-wave (64-thread) blocks, LPT order.
// Register-staged + prefetched (T14): the whole K-tile is loaded into
// k0/k1[8] BEFORE the QK MFMA loop (16 loads share one latency window);
// the NEXT tile's K is issued right after the QK MFMAs (hidden under
// softmax+PV); the whole V-tile is loaded into vv[4][8] before softmax
// (V doesn't depend on softmax -> its latency hides under the exp pass).
// Swapped-QK^T keeps P-rows in-lane; softmax in exp2 domain; defer-rescale
// (THR=8); PV via zero-padded 16x16x32 MFMAs from registers. No LDS.
__global__ __launch_bounds__(64, 2) void flash_kernel(
    const unsigned short* __restrict__ Qb, const unsigned short* __restrict__ Kb,
    const unsigned short* __restrict__ VT, unsigned short* __restrict__ attnb) {
  const int bi = blockIdx.x;
  const int h = bi & 31, hk = h >> 2;  // REP=4
  const int qc = 63 - (bi >> 5);       // LPT: heavy chunks first
  const int l = threadIdx.x & 63;
  const int hi = l >> 4, r16 = l & 15;
  const int qrow0 = qc * 32;
  const unsigned short* Qh = Qb + (size_t)h * (SEQ * HDIM);
  const unsigned short* Kh = Kb + (size_t)hk * (SEQ * HDIM);
  const unsigned short* Vh = VT + (size_t)hk * (HDIM * SEQ);

  // Q fragments (B-operand of swapped QK): lane holds Q[qrow0+mf*16+r16][d]
  bf16x8 qf[2][2];
#pragma unroll
  for (int mf = 0; mf < 2; ++mf)
#pragma unroll
    for (int ks = 0; ks < 2; ++ks)
      qf[mf][ks] = ld_g16(Qh + (qrow0 + mf * 16 + r16) * HDIM + ks * 32 + hi * 8);

  f32x4 o[2][4] = {};
  float mrow[2] = {-1e9f, -1e9f};
  float lrow[2] = {0.f, 0.f};

  const int nkv = (qc >> 2) + 1;

  // K-tile register staging (prologue: tile 0)
  bf16x8 k0[8], k1[8];
  const unsigned short* kbase = Kh + (size_t)r16 * HDIM + hi * 8;
#pragma unroll
  for (int nf = 0; nf < 8; ++nf) {
    const unsigned short* kp = kbase + (size_t)(nf * 16) * HDIM;
    k0[nf] = ld_g16(kp);
    k1[nf] = ld_g16(kp + 32);
  }

  for (int kv = 0; kv < nkv; ++kv) {
    const int kvbase = kv * 128;
    // ---- S^T = K @ Q^T : s[mf][nf] holds q-row (qrow0+mf*16+r16),
    //      k = kvbase + nf*16 + hi*4 + r   (scale+log2e folded into Q)
    f32x4 s[2][8] = {};
#pragma unroll
    for (int nf = 0; nf < 8; ++nf) {
      s[0][nf] = __builtin_amdgcn_mfma_f32_16x16x32_bf16(k0[nf], qf[0][0], s[0][nf], 0, 0, 0);
      s[1][nf] = __builtin_amdgcn_mfma_f32_16x16x32_bf16(k0[nf], qf[1][0], s[1][nf], 0, 0, 0);
      s[0][nf] = __builtin_amdgcn_mfma_f32_16x16x32_bf16(k1[nf], qf[0][1], s[0][nf], 0, 0, 0);
      s[1][nf] = __builtin_amdgcn_mfma_f32_16x16x32_bf16(k1[nf], qf[1][1], s[1][nf], 0, 0, 0);
    }
    // ---- prefetch next K tile (consumed regs; latency hides under
    //      softmax + PV of this tile)
    if (kv + 1 < nkv) {
      const unsigned short* kp2 = kbase + (size_t)(kvbase + 128) * HDIM;
#pragma unroll
      for (int nf = 0; nf < 8; ++nf) {
        const unsigned short* kp = kp2 + (size_t)(nf * 16) * HDIM;
        k0[nf] = ld_g16(kp);
        k1[nf] = ld_g16(kp + 32);
      }
    }
    // ---- stage whole V tile (independent of softmax -> overlaps it)
    uint2 vv[4][8];
#pragma unroll
    for (int nd = 0; nd < 4; ++nd)
#pragma unroll
      for (int kt = 0; kt < 8; ++kt)
        vv[nd][kt] = *reinterpret_cast<const uint2*>(
            Vh + (size_t)(nd * 16 + r16) * SEQ + kvbase + kt * 16 + hi * 4);
    if (kv == nkv - 1) {  // diagonal tile: causal mask
#pragma unroll
      for (int mf = 0; mf < 2; ++mf) {
        int qr = qrow0 + mf * 16 + r16;
#pragma unroll
        for (int nf = 0; nf < 8; ++nf) {
          int kc = kvbase + nf * 16 + hi * 4;
#pragma unroll
          for (int r = 0; r < 4; ++r)
            if (kc + r > qr) s[mf][nf][r] = -1e9f;
        }
      }
    }
    // ---- row max: in-lane tree over 32, then 2 shfl_xor rounds
    float mx[2];
#pragma unroll
    for (int mf = 0; mf < 2; ++mf) {
      f32x4 m4 = s[mf][0];
#pragma unroll
      for (int nf = 1; nf < 8; ++nf) {
        m4[0] = fmaxf(m4[0], s[mf][nf][0]); m4[1] = fmaxf(m4[1], s[mf][nf][1]);
        m4[2] = fmaxf(m4[2], s[mf][nf][2]); m4[3] = fmaxf(m4[3], s[mf][nf][3]);
      }
      float v = fmaxf(fmaxf(m4[0], m4[1]), fmaxf(m4[2], m4[3]));
      v = fmaxf(v, __shfl_xor(v, 16));
      v = fmaxf(v, __shfl_xor(v, 32));
      mx[mf] = v;
    }
    // ---- defer-rescale (THR=8 in log2 domain)
    if (!__all(fmaxf(mx[0] - mrow[0], mx[1] - mrow[1]) <= 8.0f)) {
#pragma unroll
      for (int mf = 0; mf < 2; ++mf) {
        float mn = fmaxf(mrow[mf], mx[mf]);
        float al = fexp2(mrow[mf] - mn);
        mrow[mf] = mn;
        lrow[mf] *= al;
#pragma unroll
        for (int r = 0; r < 4; ++r) {
          float alr = __shfl(al, hi * 4 + r);
#pragma unroll
          for (int nd = 0; nd < 4; ++nd) o[mf][nd][r] *= alr;
        }
      }
    }
    // ---- P = exp2(S - m) in place, row sum (in-lane + 2 shfl rounds)
#pragma unroll
    for (int mf = 0; mf < 2; ++mf) {
      f32x4 a4 = {0.f, 0.f, 0.f, 0.f};
#pragma unroll
      for (int nf = 0; nf < 8; ++nf) {
#pragma unroll
        for (int r = 0; r < 4; ++r) {
          float p = fexp2(s[mf][nf][r] - mrow[mf]);
          s[mf][nf][r] = p;
          a4[r] += p;
        }
      }
      float rs = (a4[0] + a4[1]) + (a4[2] + a4[3]);
      rs += __shfl_xor(rs, 16);
      rs += __shfl_xor(rs, 32);
      lrow[mf] += rs;
    }
    // ---- O += P @ V via zero-padded 16x16x32 (k-slot labels hi*8+j,
    //      j<4 real = k16 hi*4+j, j>=4 zero on both operands)
#pragma unroll
    for (int kt = 0; kt < 8; ++kt) {
      bf16x8 pa[2];
#pragma unroll
      for (int mf = 0; mf < 2; ++mf) {
        bf16x8 p = {};
        p[0] = (__bf16)s[mf][kt][0];
        p[1] = (__bf16)s[mf][kt][1];
        p[2] = (__bf16)s[mf][kt][2];
        p[3] = (__bf16)s[mf][kt][3];
        pa[mf] = p;
      }
#pragma unroll
      for (int nd = 0; nd < 4; ++nd) {
        uint4 u; u.x = vv[nd][kt].x; u.y = vv[nd][kt].y; u.z = 0u; u.w = 0u;
        bf16x8 vb = __builtin_bit_cast(bf16x8, u);
        o[0][nd] = __builtin_amdgcn_mfma_f32_16x16x32_bf16(pa[0], vb, o[0][nd], 0, 0, 0);
        o[1][nd] = __builtin_amdgcn_mfma_f32_16x16x32_bf16(pa[1], vb, o[1][nd], 0, 0, 0);
      }
    }
  }
  // ---- normalize + store attn[s][h*64+d]
#pragma unroll
  for (int mf = 0; mf < 2; ++mf) {
    float linv = 1.0f / lrow[mf];
#pragma unroll
    for (int r = 0; r < 4; ++r) {
      float lr = __shfl(linv, hi * 4 + r);
      int srow = qrow0 + mf * 16 + hi * 4 + r;
#pragma unroll
      for (int nd = 0; nd < 4; ++nd) {
        int d = nd * 16 + r16;
        attnb[(size_t)srow * 2048 + h * 64 + d] = f2bf(o[mf][nd][r] * lr);
      }
    }
  }
}

// ---------------------------------------------------------------- launch
extern "C" void kernel_launch(void* const* d_in, const int* in_sizes, int n_in,
                              void* d_out, int out_size, void* d_ws,
                              size_t ws_size, hipStream_t stream) {
  const float* x     = (const float*)d_in[0];
  const float* freqs = (const float*)d_in[1];
  // d_in[2] = mask (unused; causality computed analytically)
  const float* Wq = (const float*)d_in[3];
  const float* Wk = (const float*)d_in[4];
  const float* Wv = (const float*)d_in[5];
  const float* Wo = (const float*)d_in[6];
  float* out = (float*)d_out;
  char* ws = (char*)d_ws;
  const size_t MB = 1024 * 1024;
  // ws layout (48 MB total)
  unsigned short* xb    = (unsigned short*)(ws);            // 8 MB  x bf16
  unsigned short* WqkvT = (unsigned short*)(ws + 8 * MB);   // 12 MB [3072][2048]
  unsigned short* WoT   = (unsigned short*)(ws + 20 * MB);  // 8 MB  [2048][2048]
  unsigned short* Qbuf  = (unsigned short*)(ws + 28 * MB);  // 8 MB  [32][2048][64]
  unsigned short* Kbuf  = (unsigned short*)(ws + 36 * MB);  // 2 MB  [8][2048][64]
  unsigned short* Vt    = (unsigned short*)(ws + 38 * MB);  // 2 MB  [8][64][2048]
  unsigned short* attnb = (unsigned short*)(ws + 40 * MB);  // 8 MB  [2048][2048]

  conv_x_kernel<<<dim3(2048), dim3(256), 0, stream>>>(x, xb);
  tr_qkv_kernel<<<dim3(64, 96), dim3(32, 8), 0, stream>>>(Wq, Wk, Wv, WqkvT);
  tr_wo_kernel<<<dim3(64, 64), dim3(32, 8), 0, stream>>>(Wo, WoT);
  gemm_kernel<0><<<dim3(768), dim3(256), 0, stream>>>(
      xb, WqkvT, freqs, Qbuf, Kbuf, Vt, (float*)nullptr, NQKV, 2048, 768);
  flash_kernel<<<dim3(2048), dim3(64), 0, stream>>>(Qbuf, Kbuf, Vt, attnb);
  gemm_kernel<1><<<dim3(512), dim3(256), 0, stream>>>(
      attnb, WoT, (const float*)nullptr, (unsigned short*)nullptr,
      (unsigned short*)nullptr, (unsigned short*)nullptr, out, 2048, 2048, 512);
}

// Round 9
// 287.691 us; speedup vs baseline: 1.2037x; 1.2037x over previous
//
#include <hip/hip_runtime.h>
#include <stdint.h>

// Problem constants (B=1)
#define SEQ   2048
#define EDIM  2048
#define NHQ   32
#define NHKV  8
#define HDIM  64
#define NQKV  3072   // 2048 (Q) + 512 (K) + 512 (V)

#define LOG2E 1.4426950408889634f

typedef __bf16 bf16x8 __attribute__((ext_vector_type(8)));
typedef float  f32x4  __attribute__((ext_vector_type(4)));

typedef __attribute__((address_space(1))) void gvoid;
typedef __attribute__((address_space(3))) void lvoid;

// fp32 -> bf16 bits, round-to-nearest-even
__device__ __forceinline__ unsigned short f2bf(float f) {
  unsigned int u = __builtin_bit_cast(unsigned int, f);
  u += 0x7FFFu + ((u >> 16) & 1u);
  return (unsigned short)(u >> 16);
}

// pack two fp32 -> one u32 of 2x bf16 (lo, hi)
__device__ __forceinline__ unsigned int pk2bf(float lo, float hi) {
  return (unsigned)f2bf(lo) | ((unsigned)f2bf(hi) << 16);
}

__device__ __forceinline__ float fexp2(float x) {
#if __has_builtin(__builtin_amdgcn_exp2f)
  return __builtin_amdgcn_exp2f(x);
#else
  return exp2f(x);
#endif
}

__device__ __forceinline__ bf16x8 ld_g16(const unsigned short* p) {
  uint4 u = *reinterpret_cast<const uint4*>(p);
  return __builtin_bit_cast(bf16x8, u);
}

// async global->LDS, 16B per lane. LDS dest is wave-uniform base + lane*16.
__device__ __forceinline__ void stage16(const void* g, void* l) {
  __builtin_amdgcn_global_load_lds((gvoid*)g, (lvoid*)l, 16, 0, 0);
}

// ---------------------------------------------------------------- conv x
__global__ __launch_bounds__(256) void conv_x_kernel(
    const float* __restrict__ x, unsigned short* __restrict__ xb) {
  int i = (blockIdx.x * 256 + threadIdx.x) * 8;
  float4 a = *reinterpret_cast<const float4*>(x + i);
  float4 b = *reinterpret_cast<const float4*>(x + i + 4);
  uint4 o;
  o.x = pk2bf(a.x, a.y);
  o.y = pk2bf(a.z, a.w);
  o.z = pk2bf(b.x, b.y);
  o.w = pk2bf(b.z, b.w);
  *reinterpret_cast<uint4*>(xb + i) = o;
}

// ------------------------------------------------- transpose W -> B^T bf16
// Builds WqkvT[n][k] (3072 x 2048) from Wq|Wk|Wv (k-major fp32).
__global__ __launch_bounds__(256) void tr_qkv_kernel(
    const float* __restrict__ Wq, const float* __restrict__ Wk,
    const float* __restrict__ Wv, unsigned short* __restrict__ Bt) {
  __shared__ float tile[32][33];
  const int tx = threadIdx.x, ty = threadIdx.y;
  const int kb = blockIdx.x * 32, nb = blockIdx.y * 32;
#pragma unroll
  for (int i = 0; i < 4; ++i) {
    int k = kb + ty + i * 8;
    int n = nb + tx;
    float v;
    if (n < 2048)      v = Wq[k * 2048 + n];
    else if (n < 2560) v = Wk[k * 512 + (n - 2048)];
    else               v = Wv[k * 512 + (n - 2560)];
    tile[ty + i * 8][tx] = v;
  }
  __syncthreads();
#pragma unroll
  for (int i = 0; i < 4; ++i) {
    int n = nb + ty + i * 8;
    int k = kb + tx;
    Bt[n * 2048 + k] = f2bf(tile[tx][ty + i * 8]);
  }
}

__global__ __launch_bounds__(256) void tr_wo_kernel(
    const float* __restrict__ Wo, unsigned short* __restrict__ Bt) {
  __shared__ float tile[32][33];
  const int tx = threadIdx.x, ty = threadIdx.y;
  const int kb = blockIdx.x * 32, nb = blockIdx.y * 32;
#pragma unroll
  for (int i = 0; i < 4; ++i)
    tile[ty + i * 8][tx] = Wo[(kb + ty + i * 8) * 2048 + nb + tx];
  __syncthreads();
#pragma unroll
  for (int i = 0; i < 4; ++i)
    Bt[(nb + ty + i * 8) * 2048 + kb + tx] = f2bf(tile[tx][ty + i * 8]);
}

// ---------------------------------------------------------------- GEMM
// C(M x N) = A(M x K, bf16 row-major) * Bt(N x K, bf16 row-major)^T
// BM=128, BN=64, BK=64. 4 waves (2x2); each wave owns 64x32 = 4x2 16x16
// frags. Grid is 1-D with bijective XCD swizzle (nwg%8==0).
// LDS: double-buffered As[128][64] + Bs[64][64] (48 KB) via global_load_lds
// with BOTH-SIDES XOR swizzle -> conflict-free ds_read_b128.
// MODE 0: epilogue = RoPE + split-store to Q[h][s][d], K[h][s][d], VT[h][d][s]
// MODE 1: plain fp32 store to Cout (N_=2048)
template <int MODE>
__global__ __launch_bounds__(256) void gemm_kernel(
    const unsigned short* __restrict__ A, const unsigned short* __restrict__ Bt,
    const float* __restrict__ freqs, unsigned short* __restrict__ Qb,
    unsigned short* __restrict__ Kb, unsigned short* __restrict__ VT,
    float* __restrict__ Cout, int N_, int K, int nwg) {
  __shared__ alignas(16) unsigned short As[2][128 * 64];
  __shared__ alignas(16) unsigned short Bs[2][64 * 64];
  const int t = threadIdx.x;
  const int w = t >> 6, l = t & 63;
  const int q = l >> 4, r16 = l & 15;
  const int wr = w >> 1, wc = w & 1;
  // bijective XCD swizzle (nwg % 8 == 0)
  const int cpx = nwg >> 3;
  const int id = (blockIdx.x & 7) * cpx + (blockIdx.x >> 3);
  const int brow = (id & 15) * 128;        // M=2048 -> 16 m-tiles
  const int bcol = (id >> 4) * 64;
  const unsigned short* Arow = A + (size_t)brow * K;
  const unsigned short* Brow = Bt + (size_t)bcol * K;
  f32x4 acc[4][2] = {};

#define STAGE_TILE(buf, ktb)                                                  \
  {                                                                           \
    _Pragma("unroll") for (int it = 0; it < 4; ++it) {                        \
      int sg = it * 256 + t;                                                  \
      int row = sg >> 3, ks = sg & 7;                                         \
      stage16(Arow + (size_t)row * K + (ktb) + ((ks ^ (row & 7)) << 3),       \
              (char*)As[buf] + sg * 16);                                      \
    }                                                                         \
    _Pragma("unroll") for (int it = 0; it < 2; ++it) {                        \
      int sg = it * 256 + t;                                                  \
      int row = sg >> 3, ks = sg & 7;                                         \
      stage16(Brow + (size_t)row * K + (ktb) + ((ks ^ (row & 7)) << 3),       \
              (char*)Bs[buf] + sg * 16);                                      \
    }                                                                         \
  }

  STAGE_TILE(0, 0)
  __syncthreads();

  for (int kt = 0; kt < K; kt += 64) {
    const int cur = (kt >> 6) & 1;
    if (kt + 64 < K) STAGE_TILE(cur ^ 1, kt + 64)
#pragma unroll
    for (int kk = 0; kk < 2; ++kk) {
      bf16x8 af[4], bfr[2];
#pragma unroll
      for (int mf = 0; mf < 4; ++mf) {
        int arow = wr * 64 + mf * 16 + r16;
        int slot = ((kk << 2) + q) ^ (arow & 7);
        af[mf] = *(const bf16x8*)(As[cur] + arow * 64 + slot * 8);
      }
#pragma unroll
      for (int nf = 0; nf < 2; ++nf) {
        int brw = wc * 32 + nf * 16 + r16;
        int slot = ((kk << 2) + q) ^ (brw & 7);
        bfr[nf] = *(const bf16x8*)(Bs[cur] + brw * 64 + slot * 8);
      }
#pragma unroll
      for (int mf = 0; mf < 4; ++mf)
#pragma unroll
        for (int nf = 0; nf < 2; ++nf)
          acc[mf][nf] = __builtin_amdgcn_mfma_f32_16x16x32_bf16(
              af[mf], bfr[nf], acc[mf][nf], 0, 0, 0);
    }
    __syncthreads();
  }

  // Epilogue. C-frag layout: col = lane&15, row = (lane>>4)*4 + reg.
#pragma unroll
  for (int mf = 0; mf < 4; ++mf) {
#pragma unroll
    for (int nf = 0; nf < 2; ++nf) {
      int j = bcol + wc * 32 + nf * 16 + r16;
#pragma unroll
      for (int reg = 0; reg < 4; ++reg) {
        float v = acc[mf][nf][reg];
        int srow = brow + wr * 64 + mf * 16 + q * 4 + reg;
        if (MODE == 1) {
          Cout[(size_t)srow * N_ + j] = v;
        } else {
          // column pairs (2i,2i+1) sit on adjacent lanes -> shfl_xor(1)
          float pv = __shfl_xor(v, 1);
          int d = j & 63;
          if (j < 2048) {  // Q, RoPE + (log2e)/sqrt(D) pre-scale
            float2 f = *reinterpret_cast<const float2*>(
                freqs + ((size_t)srow * 32 + (d >> 1)) * 2);
            float ov = (d & 1) ? (pv * f.y + v * f.x) : (v * f.x - pv * f.y);
            Qb[(size_t)(j >> 6) * (SEQ * HDIM) + srow * HDIM + d] =
                f2bf(ov * (0.125f * LOG2E));
          } else if (j < 2560) {  // K, RoPE
            float2 f = *reinterpret_cast<const float2*>(
                freqs + ((size_t)srow * 32 + (d >> 1)) * 2);
            float ov = (d & 1) ? (pv * f.y + v * f.x) : (v * f.x - pv * f.y);
            Kb[(size_t)((j - 2048) >> 6) * (SEQ * HDIM) + srow * HDIM + d] =
                f2bf(ov);
          } else {  // V, stored transposed [h][d][s]
            VT[(size_t)((j - 2560) >> 6) * (HDIM * SEQ) + d * SEQ + srow] =
                f2bf(v);
          }
        }
      }
    }
  }
#undef STAGE_TILE
}

// ------------------------------------------------------------ flash attn
// 32 q-rows/wave, KVBLK=128; 1-wave (64-thread) blocks, LPT order.
// K-tile register staging + next-tile prefetch ONLY (round-8 lesson: adding
// the V-tile staging on top pushed live state to ~240 VGPR -> the allocator
// clamped at 128 and spilled 162 MB/dispatch to scratch). The K tile's 16
// loads are batched in one latency window before QK; the NEXT tile's 16
// loads are issued right after QK and fly under softmax+PV. V loads stay
// inline in the PV loop (they pipeline against the previous kt's MFMAs).
// Peak live ~200 VGPR; __launch_bounds__(64,1) grants the budget (empirical:
// (64,3)->84-cap, (64,2)->128-cap). Swapped-QK^T, exp2-domain softmax,
// defer-rescale (THR=8), zero-padded PV MFMAs. No LDS.
__global__ __launch_bounds__(64, 1) void flash_kernel(
    const unsigned short* __restrict__ Qb, const unsigned short* __restrict__ Kb,
    const unsigned short* __restrict__ VT, unsigned short* __restrict__ attnb) {
  const int bi = blockIdx.x;
  const int h = bi & 31, hk = h >> 2;  // REP=4
  const int qc = 63 - (bi >> 5);       // LPT: heavy chunks first
  const int l = threadIdx.x & 63;
  const int hi = l >> 4, r16 = l & 15;
  const int qrow0 = qc * 32;
  const unsigned short* Qh = Qb + (size_t)h * (SEQ * HDIM);
  const unsigned short* Kh = Kb + (size_t)hk * (SEQ * HDIM);
  const unsigned short* Vh = VT + (size_t)hk * (HDIM * SEQ);

  // Q fragments (B-operand of swapped QK): lane holds Q[qrow0+mf*16+r16][d]
  bf16x8 qf[2][2];
#pragma unroll
  for (int mf = 0; mf < 2; ++mf)
#pragma unroll
    for (int ks = 0; ks < 2; ++ks)
      qf[mf][ks] = ld_g16(Qh + (qrow0 + mf * 16 + r16) * HDIM + ks * 32 + hi * 8);

  f32x4 o[2][4] = {};
  float mrow[2] = {-1e9f, -1e9f};
  float lrow[2] = {0.f, 0.f};

  const int nkv = (qc >> 2) + 1;

  // K-tile register staging (prologue: tile 0) — 16 loads, one window
  bf16x8 k0[8], k1[8];
  const unsigned short* kbase = Kh + (size_t)r16 * HDIM + hi * 8;
#pragma unroll
  for (int nf = 0; nf < 8; ++nf) {
    const unsigned short* kp = kbase + (size_t)(nf * 16) * HDIM;
    k0[nf] = ld_g16(kp);
    k1[nf] = ld_g16(kp + 32);
  }

  for (int kv = 0; kv < nkv; ++kv) {
    const int kvbase = kv * 128;
    // ---- S^T = K @ Q^T : s[mf][nf] holds q-row (qrow0+mf*16+r16),
    //      k = kvbase + nf*16 + hi*4 + r   (scale+log2e folded into Q)
    f32x4 s[2][8] = {};
#pragma unroll
    for (int nf = 0; nf < 8; ++nf) {
      s[0][nf] = __builtin_amdgcn_mfma_f32_16x16x32_bf16(k0[nf], qf[0][0], s[0][nf], 0, 0, 0);
      s[1][nf] = __builtin_amdgcn_mfma_f32_16x16x32_bf16(k0[nf], qf[1][0], s[1][nf], 0, 0, 0);
      s[0][nf] = __builtin_amdgcn_mfma_f32_16x16x32_bf16(k1[nf], qf[0][1], s[0][nf], 0, 0, 0);
      s[1][nf] = __builtin_amdgcn_mfma_f32_16x16x32_bf16(k1[nf], qf[1][1], s[1][nf], 0, 0, 0);
    }
    // ---- prefetch next K tile into the same regs (dead after QK MFMAs);
    //      latency hides under softmax + PV of this tile
    if (kv + 1 < nkv) {
      const unsigned short* kp2 = kbase + (size_t)(kvbase + 128) * HDIM;
#pragma unroll
      for (int nf = 0; nf < 8; ++nf) {
        const unsigned short* kp = kp2 + (size_t)(nf * 16) * HDIM;
        k0[nf] = ld_g16(kp);
        k1[nf] = ld_g16(kp + 32);
      }
    }
    if (kv == nkv - 1) {  // diagonal tile: causal mask
#pragma unroll
      for (int mf = 0; mf < 2; ++mf) {
        int qr = qrow0 + mf * 16 + r16;
#pragma unroll
        for (int nf = 0; nf < 8; ++nf) {
          int kc = kvbase + nf * 16 + hi * 4;
#pragma unroll
          for (int r = 0; r < 4; ++r)
            if (kc + r > qr) s[mf][nf][r] = -1e9f;
        }
      }
    }
    // ---- row max: in-lane tree over 32, then 2 shfl_xor rounds
    float mx[2];
#pragma unroll
    for (int mf = 0; mf < 2; ++mf) {
      f32x4 m4 = s[mf][0];
#pragma unroll
      for (int nf = 1; nf < 8; ++nf) {
        m4[0] = fmaxf(m4[0], s[mf][nf][0]); m4[1] = fmaxf(m4[1], s[mf][nf][1]);
        m4[2] = fmaxf(m4[2], s[mf][nf][2]); m4[3] = fmaxf(m4[3], s[mf][nf][3]);
      }
      float v = fmaxf(fmaxf(m4[0], m4[1]), fmaxf(m4[2], m4[3]));
      v = fmaxf(v, __shfl_xor(v, 16));
      v = fmaxf(v, __shfl_xor(v, 32));
      mx[mf] = v;
    }
    // ---- defer-rescale (THR=8 in log2 domain)
    if (!__all(fmaxf(mx[0] - mrow[0], mx[1] - mrow[1]) <= 8.0f)) {
#pragma unroll
      for (int mf = 0; mf < 2; ++mf) {
        float mn = fmaxf(mrow[mf], mx[mf]);
        float al = fexp2(mrow[mf] - mn);
        mrow[mf] = mn;
        lrow[mf] *= al;
#pragma unroll
        for (int r = 0; r < 4; ++r) {
          float alr = __shfl(al, hi * 4 + r);
#pragma unroll
          for (int nd = 0; nd < 4; ++nd) o[mf][nd][r] *= alr;
        }
      }
    }
    // ---- P = exp2(S - m) in place, row sum (in-lane + 2 shfl rounds)
#pragma unroll
    for (int mf = 0; mf < 2; ++mf) {
      f32x4 a4 = {0.f, 0.f, 0.f, 0.f};
#pragma unroll
      for (int nf = 0; nf < 8; ++nf) {
#pragma unroll
        for (int r = 0; r < 4; ++r) {
          float p = fexp2(s[mf][nf][r] - mrow[mf]);
          s[mf][nf][r] = p;
          a4[r] += p;
        }
      }
      float rs = (a4[0] + a4[1]) + (a4[2] + a4[3]);
      rs += __shfl_xor(rs, 16);
      rs += __shfl_xor(rs, 32);
      lrow[mf] += rs;
    }
    // ---- O += P @ V via zero-padded 16x16x32 (k-slot labels hi*8+j,
    //      j<4 real = k16 hi*4+j, j>=4 zero on both operands).
    //      V loads inline: each kt's 4 loads pipeline vs prev kt's MFMAs.
#pragma unroll
    for (int kt = 0; kt < 8; ++kt) {
      bf16x8 pa[2];
#pragma unroll
      for (int mf = 0; mf < 2; ++mf) {
        bf16x8 p = {};
        p[0] = (__bf16)s[mf][kt][0];
        p[1] = (__bf16)s[mf][kt][1];
        p[2] = (__bf16)s[mf][kt][2];
        p[3] = (__bf16)s[mf][kt][3];
        pa[mf] = p;
      }
#pragma unroll
      for (int nd = 0; nd < 4; ++nd) {
        uint2 v2 = *reinterpret_cast<const uint2*>(
            Vh + (size_t)(nd * 16 + r16) * SEQ + kvbase + kt * 16 + hi * 4);
        uint4 u; u.x = v2.x; u.y = v2.y; u.z = 0u; u.w = 0u;
        bf16x8 vb = __builtin_bit_cast(bf16x8, u);
        o[0][nd] = __builtin_amdgcn_mfma_f32_16x16x32_bf16(pa[0], vb, o[0][nd], 0, 0, 0);
        o[1][nd] = __builtin_amdgcn_mfma_f32_16x16x32_bf16(pa[1], vb, o[1][nd], 0, 0, 0);
      }
    }
  }
  // ---- normalize + store attn[s][h*64+d]
#pragma unroll
  for (int mf = 0; mf < 2; ++mf) {
    float linv = 1.0f / lrow[mf];
#pragma unroll
    for (int r = 0; r < 4; ++r) {
      float lr = __shfl(linv, hi * 4 + r);
      int srow = qrow0 + mf * 16 + hi * 4 + r;
#pragma unroll
      for (int nd = 0; nd < 4; ++nd) {
        int d = nd * 16 + r16;
        attnb[(size_t)srow * 2048 + h * 64 + d] = f2bf(o[mf][nd][r] * lr);
      }
    }
  }
}

// ---------------------------------------------------------------- launch
extern "C" void kernel_launch(void* const* d_in, const int* in_sizes, int n_in,
                              void* d_out, int out_size, void* d_ws,
                              size_t ws_size, hipStream_t stream) {
  const float* x     = (const float*)d_in[0];
  const float* freqs = (const float*)d_in[1];
  // d_in[2] = mask (unused; causality computed analytically)
  const float* Wq = (const float*)d_in[3];
  const float* Wk = (const float*)d_in[4];
  const float* Wv = (const float*)d_in[5];
  const float* Wo = (const float*)d_in[6];
  float* out = (float*)d_out;
  char* ws = (char*)d_ws;
  const size_t MB = 1024 * 1024;
  // ws layout (48 MB total)
  unsigned short* xb    = (unsigned short*)(ws);            // 8 MB  x bf16
  unsigned short* WqkvT = (unsigned short*)(ws + 8 * MB);   // 12 MB [3072][2048]
  unsigned short* WoT   = (unsigned short*)(ws + 20 * MB);  // 8 MB  [2048][2048]
  unsigned short* Qbuf  = (unsigned short*)(ws + 28 * MB);  // 8 MB  [32][2048][64]
  unsigned short* Kbuf  = (unsigned short*)(ws + 36 * MB);  // 2 MB  [8][2048][64]
  unsigned short* Vt    = (unsigned short*)(ws + 38 * MB);  // 2 MB  [8][64][2048]
  unsigned short* attnb = (unsigned short*)(ws + 40 * MB);  // 8 MB  [2048][2048]

  conv_x_kernel<<<dim3(2048), dim3(256), 0, stream>>>(x, xb);
  tr_qkv_kernel<<<dim3(64, 96), dim3(32, 8), 0, stream>>>(Wq, Wk, Wv, WqkvT);
  tr_wo_kernel<<<dim3(64, 64), dim3(32, 8), 0, stream>>>(Wo, WoT);
  gemm_kernel<0><<<dim3(768), dim3(256), 0, stream>>>(
      xb, WqkvT, freqs, Qbuf, Kbuf, Vt, (float*)nullptr, NQKV, 2048, 768);
  flash_kernel<<<dim3(2048), dim3(64), 0, stream>>>(Qbuf, Kbuf, Vt, attnb);
  gemm_kernel<1><<<dim3(512), dim3(256), 0, stream>>>(
      attnb, WoT, (const float*)nullptr, (unsigned short*)nullptr,
      (unsigned short*)nullptr, (unsigned short*)nullptr, out, 2048, 2048, 512);
}